// Round 12
// baseline (68.885 us; speedup 1.0000x reference)
//
#include <hip/hip_runtime.h>
#include <math.h>

#define B 128
#define E 6
#define IN_DIM 1664
#define H_DIM 512
#define OUT_DIM 618
#define ZD 32
#define K2 544
#define S1 26             // L1 split-K (KPB=2)
#define S23 17            // L2/L3 split-K (16x1kb + 1 z-split)

typedef __attribute__((ext_vector_type(8))) short short8;
typedef __attribute__((ext_vector_type(4))) float f32x4;
union U128 { uint4 u4; short8 s8; ushort us[8]; };

__device__ __forceinline__ ushort f2bf(float f) {   // fp32 -> bf16 RNE
    uint u = __float_as_uint(f);
    u += 0x7fffu + ((u >> 16) & 1u);
    return (ushort)(u >> 16);
}
__device__ __forceinline__ uint pk2(float a, float b) {
    return (uint)f2bf(a) | ((uint)f2bf(b) << 16);
}
__device__ __forceinline__ float elu1(float x) { return x < 0.f ? expm1f(x) : x; }

// MFMA frag math (HW-validated r3-r11):
//  A frag (kb,m): lane l -> row 16m+(l&15), k = 32kb+(l>>4)*8+j
//  B frag (kb,nf): lane l -> col 16nf+(l&15), k = 32kb+(l>>4)*8+j
//  C/D: col = l&15, row = (l>>4)*4 + r

// ---------------------------------------------------------------------------
// init_bias: y1,y2,y3 <- coef-blended biases; zero the L3 fixup counters.
// ---------------------------------------------------------------------------
__global__ __launch_bounds__(256) void init_bias(
    const float* __restrict__ coef,
    const float* __restrict__ b1, const float* __restrict__ b2,
    const float* __restrict__ b3,
    float* __restrict__ y1, float* __restrict__ y2, float* __restrict__ y3,
    int* __restrict__ cnt)
{
    const int idx = blockIdx.x * 256 + threadIdx.x;
    if (blockIdx.x == 0 && threadIdx.x < 32) cnt[threadIdx.x] = 0;
    if (idx >= B * (2 * H_DIM + OUT_DIM)) return;
    const int b = idx / (2 * H_DIM + OUT_DIM);
    const int o = idx - b * (2 * H_DIM + OUT_DIM);
    float ce[E];
    #pragma unroll
    for (int e = 0; e < E; ++e) ce[e] = coef[b * E + e];
    float v = 0.f;
    if (o < H_DIM) {
        #pragma unroll
        for (int e = 0; e < E; ++e) v = fmaf(ce[e], b1[e * H_DIM + o], v);
        y1[b * H_DIM + o] = v;
    } else if (o < 2 * H_DIM) {
        const int oo = o - H_DIM;
        #pragma unroll
        for (int e = 0; e < E; ++e) v = fmaf(ce[e], b2[e * H_DIM + oo], v);
        y2[b * H_DIM + oo] = v;
    } else {
        const int oo = o - 2 * H_DIM;
        #pragma unroll
        for (int e = 0; e < E; ++e) v = fmaf(ce[e], b3[e * OUT_DIM + oo], v);
        y3[b * OUT_DIM + oo] = v;
    }
}

// ---------------------------------------------------------------------------
// gemm1: L1, block tile 128x32, KPB=2 (12 steps), grid 16x26. A-frags from
// fp32 x*coef in-register (both kb's x loaded up front); W fp32 -> bf16 ->
// LDS frags (dbuf, 3-deep W reg-prefetch ring, 1 barrier/step). Epilogue:
// atomicAdd into y1 (bias pre-initialized).
// ---------------------------------------------------------------------------
__global__ __launch_bounds__(256) void gemm1(
    const float* __restrict__ x,     // [B][IN_DIM]
    const float* __restrict__ coef,  // [B][E]
    const float* __restrict__ w,     // [E][IN_DIM][H_DIM]
    float* __restrict__ y1)          // [B][H_DIM] accum
{
    constexpr int NS = E * 2;        // 12
    const int tid = threadIdx.x;
    const int l = tid & 63, wv = tid >> 6;
    const int n0 = blockIdx.x * 32, kb0 = blockIdx.y * 2;
    const int tn = tid & 31, tkq = tid >> 5;
    const int lp = ((tkq >> 1) << 4) | (tn & 15);
    const int fI = tn >> 4, j0 = (tkq & 1) << 2;
    const int colW = n0 + tn;
    const int row0 = 32 * wv + (l & 15), row1 = row0 + 16, kq = l >> 4;

    __shared__ ushort bs[2][2][64][8];

    float ce0[E], ce1[E];
    #pragma unroll
    for (int e = 0; e < E; ++e) {
        ce0[e] = coef[row0 * E + e];
        ce1[e] = coef[row1 * E + e];
    }

    auto ld_B = [&](int s, float* r) {
        const int e = s % E, kb = kb0 + s / E;
        const float* src = w + ((size_t)e * IN_DIM + kb * 32 + tkq * 4) * H_DIM + colW;
        #pragma unroll
        for (int j = 0; j < 4; ++j) r[j] = src[(size_t)j * H_DIM];
    };

    // x for both kb's, up front (L2-resident, reused 6 steps each)
    float4 xreg[2][4];
    #pragma unroll
    for (int kbi = 0; kbi < 2; ++kbi) {
        const float* p0 = x + (size_t)row0 * IN_DIM + (kb0 + kbi) * 32 + kq * 8;
        const float* p1 = x + (size_t)row1 * IN_DIM + (kb0 + kbi) * 32 + kq * 8;
        xreg[kbi][0] = *reinterpret_cast<const float4*>(p0);
        xreg[kbi][1] = *reinterpret_cast<const float4*>(p0 + 4);
        xreg[kbi][2] = *reinterpret_cast<const float4*>(p1);
        xreg[kbi][3] = *reinterpret_cast<const float4*>(p1 + 4);
    }

    f32x4 acc00 = {0.f,0.f,0.f,0.f}, acc01 = {0.f,0.f,0.f,0.f};
    f32x4 acc10 = {0.f,0.f,0.f,0.f}, acc11 = {0.f,0.f,0.f,0.f};

    float wreg[3][4];                    // 3-deep prefetch ring
    ld_B(0, wreg[0]); ld_B(1, wreg[1]); ld_B(2, wreg[2]);

    #pragma unroll
    for (int s = 0; s < NS; ++s) {
        const int rs = s % 3, pb_ = s & 1, e = s % E, kbi = s / E;
        uint2 pk;
        pk.x = pk2(wreg[rs][0], wreg[rs][1]);
        pk.y = pk2(wreg[rs][2], wreg[rs][3]);
        *reinterpret_cast<uint2*>(&bs[pb_][fI][lp][j0]) = pk;

        const float4* xc = xreg[kbi];
        U128 a0, a1;
        a0.us[0] = f2bf(xc[0].x * ce0[e]); a0.us[1] = f2bf(xc[0].y * ce0[e]);
        a0.us[2] = f2bf(xc[0].z * ce0[e]); a0.us[3] = f2bf(xc[0].w * ce0[e]);
        a0.us[4] = f2bf(xc[1].x * ce0[e]); a0.us[5] = f2bf(xc[1].y * ce0[e]);
        a0.us[6] = f2bf(xc[1].z * ce0[e]); a0.us[7] = f2bf(xc[1].w * ce0[e]);
        a1.us[0] = f2bf(xc[2].x * ce1[e]); a1.us[1] = f2bf(xc[2].y * ce1[e]);
        a1.us[2] = f2bf(xc[2].z * ce1[e]); a1.us[3] = f2bf(xc[2].w * ce1[e]);
        a1.us[4] = f2bf(xc[3].x * ce1[e]); a1.us[5] = f2bf(xc[3].y * ce1[e]);
        a1.us[6] = f2bf(xc[3].z * ce1[e]); a1.us[7] = f2bf(xc[3].w * ce1[e]);

        if (s + 3 < NS) ld_B(s + 3, wreg[rs]);   // refill freed ring slot

        __syncthreads();
        U128 b0, b1;
        b0.u4 = *reinterpret_cast<const uint4*>(&bs[pb_][0][l][0]);
        b1.u4 = *reinterpret_cast<const uint4*>(&bs[pb_][1][l][0]);
        acc00 = __builtin_amdgcn_mfma_f32_16x16x32_bf16(a0.s8, b0.s8, acc00, 0, 0, 0);
        acc01 = __builtin_amdgcn_mfma_f32_16x16x32_bf16(a0.s8, b1.s8, acc01, 0, 0, 0);
        acc10 = __builtin_amdgcn_mfma_f32_16x16x32_bf16(a1.s8, b0.s8, acc10, 0, 0, 0);
        acc11 = __builtin_amdgcn_mfma_f32_16x16x32_bf16(a1.s8, b1.s8, acc11, 0, 0, 0);
    }

    const int colB = n0 + (l & 15);
    const int rsub = (l >> 4) << 2;
    #pragma unroll
    for (int mi = 0; mi < 2; ++mi) {
        const int row = wv * 32 + mi * 16 + rsub;
        const f32x4 c0 = mi ? acc10 : acc00;
        const f32x4 c1 = mi ? acc11 : acc01;
        #pragma unroll
        for (int r = 0; r < 4; ++r) {
            atomicAdd(&y1[(size_t)(row + r) * H_DIM + colB],      c0[r]);
            atomicAdd(&y1[(size_t)(row + r) * H_DIM + colB + 16], c1[r]);
        }
    }
}

// ---------------------------------------------------------------------------
// gemm_mid: L2/L3, KPB=1 (6 steps), 17 splits (16 + z). Prologue: O(1) loads
// (elu(yin) or raw z). 3-deep W prefetch ring. Epilogue: atomicAdd into yout;
// optionally (FIX) split-K last-block fixup copies the finished n-tile to out.
// ---------------------------------------------------------------------------
template<bool ZS, int NW, bool GUARD, bool FIX>
__device__ __forceinline__ void gemm_mid_body(
    const float* __restrict__ yin,   // [B][H_DIM] accum(+bias) pre-ELU
    const float* __restrict__ coef,  // [B][E]
    const float* __restrict__ z,     // [B][ZD]
    const float* __restrict__ w,     // [E][K2][NW]
    float* __restrict__ yout,        // [B][NW] accum (workspace)
    float* __restrict__ out,         // [B][NW] final (FIX only)
    int* __restrict__ cnt,           // [n-tiles] fixup counters (FIX only)
    int nt, int kb0, ushort (*bs)[2][64][8])
{
    constexpr int NS = E;            // 6 steps
    const int tid = threadIdx.x;
    const int l = tid & 63, wv = tid >> 6;
    const int n0 = nt * 32;
    const int tn = tid & 31, tkq = tid >> 5;
    const int lp = ((tkq >> 1) << 4) | (tn & 15);
    const int fI = tn >> 4, j0 = (tkq & 1) << 2;
    const int colW = n0 + tn;
    const int row0 = 32 * wv + (l & 15), row1 = row0 + 16, kq = l >> 4;

    float ce0[E], ce1[E];
    #pragma unroll
    for (int e = 0; e < E; ++e) {
        ce0[e] = coef[row0 * E + e];
        ce1[e] = coef[row1 * E + e];
    }

    // ---- prologue: per-thread activations for this k-range (8 values) ----
    float v0[8], v1[8];
    if (ZS) {
        const float4 za = *reinterpret_cast<const float4*>(z + row0 * ZD + kq * 8);
        const float4 zb = *reinterpret_cast<const float4*>(z + row0 * ZD + kq * 8 + 4);
        const float4 zc = *reinterpret_cast<const float4*>(z + row1 * ZD + kq * 8);
        const float4 zd = *reinterpret_cast<const float4*>(z + row1 * ZD + kq * 8 + 4);
        v0[0]=za.x; v0[1]=za.y; v0[2]=za.z; v0[3]=za.w;
        v0[4]=zb.x; v0[5]=zb.y; v0[6]=zb.z; v0[7]=zb.w;
        v1[0]=zc.x; v1[1]=zc.y; v1[2]=zc.z; v1[3]=zc.w;
        v1[4]=zd.x; v1[5]=zd.y; v1[6]=zd.z; v1[7]=zd.w;
    } else {
        const int kk = kb0 * 32 + kq * 8;
        const float* p0 = yin + (size_t)row0 * H_DIM + kk;
        const float* p1 = yin + (size_t)row1 * H_DIM + kk;
        const float4 a = *reinterpret_cast<const float4*>(p0);
        const float4 b = *reinterpret_cast<const float4*>(p0 + 4);
        const float4 c = *reinterpret_cast<const float4*>(p1);
        const float4 d = *reinterpret_cast<const float4*>(p1 + 4);
        v0[0]=elu1(a.x); v0[1]=elu1(a.y); v0[2]=elu1(a.z); v0[3]=elu1(a.w);
        v0[4]=elu1(b.x); v0[5]=elu1(b.y); v0[6]=elu1(b.z); v0[7]=elu1(b.w);
        v1[0]=elu1(c.x); v1[1]=elu1(c.y); v1[2]=elu1(c.z); v1[3]=elu1(c.w);
        v1[4]=elu1(d.x); v1[5]=elu1(d.y); v1[6]=elu1(d.z); v1[7]=elu1(d.w);
    }

    // ---- MFMA pipeline ----
    auto ld_B = [&](int s, float* r) {
        const float* src = w + ((size_t)s * K2 + kb0 * 32 + tkq * 4) * NW + colW;
        #pragma unroll
        for (int j = 0; j < 4; ++j)
            r[j] = (!GUARD || colW < NW) ? src[(size_t)j * NW] : 0.f;
    };

    f32x4 acc00 = {0.f,0.f,0.f,0.f}, acc01 = {0.f,0.f,0.f,0.f};
    f32x4 acc10 = {0.f,0.f,0.f,0.f}, acc11 = {0.f,0.f,0.f,0.f};

    float wreg[3][4];
    ld_B(0, wreg[0]); ld_B(1, wreg[1]); ld_B(2, wreg[2]);

    #pragma unroll
    for (int s = 0; s < NS; ++s) {
        const int rs = s % 3, pb_ = s & 1;
        uint2 pk;
        pk.x = pk2(wreg[rs][0], wreg[rs][1]);
        pk.y = pk2(wreg[rs][2], wreg[rs][3]);
        *reinterpret_cast<uint2*>(&bs[pb_][fI][lp][j0]) = pk;

        U128 a0, a1;
        #pragma unroll
        for (int j = 0; j < 8; ++j) {
            a0.us[j] = f2bf(v0[j] * ce0[s]);
            a1.us[j] = f2bf(v1[j] * ce1[s]);
        }

        if (s + 3 < NS) ld_B(s + 3, wreg[rs]);

        __syncthreads();
        U128 b0, b1;
        b0.u4 = *reinterpret_cast<const uint4*>(&bs[pb_][0][l][0]);
        b1.u4 = *reinterpret_cast<const uint4*>(&bs[pb_][1][l][0]);
        acc00 = __builtin_amdgcn_mfma_f32_16x16x32_bf16(a0.s8, b0.s8, acc00, 0, 0, 0);
        acc01 = __builtin_amdgcn_mfma_f32_16x16x32_bf16(a0.s8, b1.s8, acc01, 0, 0, 0);
        acc10 = __builtin_amdgcn_mfma_f32_16x16x32_bf16(a1.s8, b0.s8, acc10, 0, 0, 0);
        acc11 = __builtin_amdgcn_mfma_f32_16x16x32_bf16(a1.s8, b1.s8, acc11, 0, 0, 0);
    }

    const int colB = n0 + (l & 15);
    const int rsub = (l >> 4) << 2;
    #pragma unroll
    for (int mi = 0; mi < 2; ++mi) {
        const int row = wv * 32 + mi * 16 + rsub;
        const f32x4 c0 = mi ? acc10 : acc00;
        const f32x4 c1 = mi ? acc11 : acc01;
        #pragma unroll
        for (int r = 0; r < 4; ++r) {
            if (!GUARD || colB < NW)
                atomicAdd(&yout[(size_t)(row + r) * NW + colB], c0[r]);
            if (!GUARD || colB + 16 < NW)
                atomicAdd(&yout[(size_t)(row + r) * NW + colB + 16], c1[r]);
        }
    }

    if (FIX) {
        // split-K fixup: last block to finish tile nt copies it to out.
        __shared__ int last;
        __threadfence();                           // release my atomics
        if (tid == 0) {
            const int old = atomicAdd(&cnt[nt], 1);
            last = (old == S23 - 1);
        }
        __syncthreads();
        if (last) {
            __threadfence();                       // acquire others' atomics
            for (int i = tid; i < 32 * B; i += 256) {
                const int row = i >> 5, col = n0 + (i & 31);
                if (!GUARD || col < NW)
                    out[(size_t)row * NW + col] = yout[(size_t)row * NW + col];
            }
        }
    }
}

__global__ __launch_bounds__(256) void gemm_l2(
    const float* __restrict__ y1, const float* __restrict__ coef,
    const float* __restrict__ z, const float* __restrict__ w2,
    float* __restrict__ y2)
{
    __shared__ ushort bs[2][2][64][8];
    const int nt = blockIdx.x, sp = blockIdx.y;
    if (sp < 16)
        gemm_mid_body<false, H_DIM, false, false>(y1, coef, z, w2, y2,
                                                  nullptr, nullptr, nt, sp, bs);
    else
        gemm_mid_body<true, H_DIM, false, false>(y1, coef, z, w2, y2,
                                                 nullptr, nullptr, nt, 16, bs);
}

__global__ __launch_bounds__(256) void gemm_l3(
    const float* __restrict__ y2, const float* __restrict__ coef,
    const float* __restrict__ z, const float* __restrict__ w3,
    float* __restrict__ y3, float* __restrict__ out, int* __restrict__ cnt)
{
    __shared__ ushort bs[2][2][64][8];
    const int nt = blockIdx.x, sp = blockIdx.y;
    if (sp < 16)
        gemm_mid_body<false, OUT_DIM, true, true>(y2, coef, z, w3, y3,
                                                  out, cnt, nt, sp, bs);
    else
        gemm_mid_body<true, OUT_DIM, true, true>(y2, coef, z, w3, y3,
                                                 out, cnt, nt, 16, bs);
}

extern "C" void kernel_launch(void* const* d_in, const int* in_sizes, int n_in,
                              void* d_out, int out_size, void* d_ws, size_t ws_size,
                              hipStream_t stream)
{
    const float* p_prev = (const float*)d_in[0];
    const float* coef   = (const float*)d_in[1];
    const float* z      = (const float*)d_in[2];
    const float* w1     = (const float*)d_in[3];
    const float* b1     = (const float*)d_in[4];
    const float* w2     = (const float*)d_in[5];
    const float* b2     = (const float*)d_in[6];
    const float* w3     = (const float*)d_in[7];
    const float* b3     = (const float*)d_in[8];
    float* out = (float*)d_out;

    // ws: y1 | y2 | y3 | cnt  (re-initialized every call by init_bias)
    float* y1 = (float*)d_ws;              // [B][512]
    float* y2 = y1 + (size_t)B * H_DIM;    // [B][512]
    float* y3 = y2 + (size_t)B * H_DIM;    // [B][618]
    int* cnt  = (int*)(y3 + (size_t)B * OUT_DIM);  // [32]

    const int TOT = B * (2 * H_DIM + OUT_DIM);
    init_bias<<<(TOT + 255) / 256, 256, 0, stream>>>(coef, b1, b2, b3,
                                                     y1, y2, y3, cnt);
    gemm1<<<dim3(16, S1), 256, 0, stream>>>(p_prev, coef, w1, y1);
    gemm_l2<<<dim3(16, S23), 256, 0, stream>>>(y1, coef, z, w2, y2);
    gemm_l3<<<dim3(20, S23), 256, 0, stream>>>(y2, coef, z, w3, y3, out, cnt);
}